// Round 1
// baseline (166.520 us; speedup 1.0000x reference)
//
#include <hip/hip_runtime.h>
#include <math.h>

#define NBINS 128
#define MAXNB 1024

// Each block accumulates per-wave private LDS histograms (native ds_add_f32 via
// unsafeAtomicAdd, no CAS loops), then writes its 128 partial sums to a private
// bin-major workspace slice ws[j*nb + b] with plain stores.
// No global atomics anywhere -> no 1024-way CAS serialization tail.
__global__ __launch_bounds__(256) void hist_kernel(const float* __restrict__ x,
                                                   const float* __restrict__ edges,
                                                   float* __restrict__ ws, int n, int nb) {
    __shared__ float sh[4][NBINS];   // per-wave private histograms (4 waves of 64)
    for (int i = threadIdx.x; i < 4 * NBINS; i += blockDim.x) ((float*)sh)[i] = 0.0f;
    __syncthreads();

    const float e0 = edges[0];
    const float res = edges[1] - e0;
    const float inv_res = 1.0f / res;
    const float C = 6.0f;                       // ndtr saturates to {0.0f,1.0f} beyond ~5.4 in f32
    const float inv_sqrt2 = 0.70710678118654752440f;
    const int w = threadIdx.x >> 6;             // wave id within block

    const int stride = gridDim.x * blockDim.x;
    for (int i = blockIdx.x * blockDim.x + threadIdx.x; i < n; i += stride) {
        float xv = x[i * 6];                    // AXIS=0 of row-major (N,6)
        float t = (xv - e0) * inv_res;          // position in bin units; z_j = j - t
        int j0 = (int)ceilf(t - C - 1.0f);
        int j1 = (int)floorf(t + C);
        j0 = max(j0, 0);
        j1 = min(j1, NBINS - 1);
        if (j0 > j1) continue;
        float cprev = 0.5f * (1.0f + erff(((float)j0 - t) * inv_sqrt2));
        for (int j = j0; j <= j1; ++j) {
            float cnext = 0.5f * (1.0f + erff(((float)(j + 1) - t) * inv_sqrt2));
            unsafeAtomicAdd(&sh[w][j], cnext - cprev);   // native ds_add_f32
            cprev = cnext;
        }
    }
    __syncthreads();

    // Flush: combine the 4 wave histograms, store to this block's slice (bin-major).
    for (int j = threadIdx.x; j < NBINS; j += blockDim.x) {
        float v = sh[0][j] + sh[1][j] + sh[2][j] + sh[3][j];
        ws[j * nb + blockIdx.x] = v;            // plain store, no atomic, no zeroing needed
    }
}

// One block, 1024 threads: 8 threads per bin sum that bin's nb partials
// (bin-major -> contiguous, coalesced), then tree-reduce, normalize, write out.
__global__ __launch_bounds__(1024) void finalize_kernel(const float* __restrict__ ws,
                                                        const float* __restrict__ edges,
                                                        float* __restrict__ out, int nb) {
    __shared__ float red[1024];
    __shared__ float vbin[NBINS];
    __shared__ float tot[NBINS];
    const int tid = threadIdx.x;
    const int j = tid >> 3;        // bin 0..127
    const int s = tid & 7;         // sub-summer 0..7

    float acc = 0.0f;
    for (int b = s; b < nb; b += 8) acc += ws[j * nb + b];
    red[tid] = acc;
    __syncthreads();
    if (s < 4) red[tid] += red[tid + 4];
    __syncthreads();
    if (s < 2) red[tid] += red[tid + 2];
    __syncthreads();
    if (s == 0) vbin[j] = red[tid] + red[tid + 1];
    __syncthreads();

    if (tid < NBINS) tot[tid] = vbin[tid];
    __syncthreads();
    for (int off = NBINS / 2; off >= 1; off >>= 1) {
        if (tid < off) tot[tid] += tot[tid + off];
        __syncthreads();
    }
    if (tid < NBINS) {
        float resv = edges[1] - edges[0];
        out[tid] = vbin[tid] / (tot[0] * resv);
    }
}

extern "C" void kernel_launch(void* const* d_in, const int* in_sizes, int n_in,
                              void* d_out, int out_size, void* d_ws, size_t ws_size,
                              hipStream_t stream) {
    const float* x     = (const float*)d_in[0];
    const float* edges = (const float*)d_in[1];
    float* out = (float*)d_out;
    float* ws  = (float*)d_ws;
    int n = in_sizes[0] / 6;

    int nb = (int)(ws_size / (NBINS * sizeof(float)));   // slices that fit in workspace
    if (nb > MAXNB) nb = MAXNB;
    if (nb < 1) nb = 1;

    hist_kernel<<<nb, 256, 0, stream>>>(x, edges, ws, n, nb);
    finalize_kernel<<<1, 1024, 0, stream>>>(ws, edges, out, nb);
}

// Round 2
// 153.454 us; speedup vs baseline: 1.0852x; 1.0852x over previous
//
#include <hip/hip_runtime.h>
#include <math.h>

#define NBINS 128
#define MAXNB 1024

// g(u) = ndtr(u+1) - ndtr(u), tabulated at step 1/16 over u in [-7.25, +6.6875].
// Since bandwidth == resolution, the per-point per-bin CDF difference is exactly
// g(j - t) with t the point position in bin units -> 13 lookups at stride 16
// with a CONSTANT fractional offset s -> Catmull-Rom weights computed once/point.
#define TK     224
#define TBASE  (-7.25f)

__global__ __launch_bounds__(256) void hist_kernel(const float* __restrict__ x,
                                                   const float* __restrict__ edges,
                                                   float* __restrict__ ws, int n, int nb) {
    __shared__ float G[TK];
    __shared__ float sh[4][NBINS];   // per-wave private histograms

    const float inv_sqrt2 = 0.70710678118654752440f;
    // Build table: one erf-pair per thread (224 <= 256), replaces ~50 erfs/thread.
    for (int k = threadIdx.x; k < TK; k += blockDim.x) {
        float u = TBASE + (float)k * 0.0625f;
        G[k] = 0.5f * (erff((u + 1.0f) * inv_sqrt2) - erff(u * inv_sqrt2));
    }
    for (int i = threadIdx.x; i < 4 * NBINS; i += blockDim.x) ((float*)sh)[i] = 0.0f;
    __syncthreads();

    const float e0 = edges[0];
    const float res = edges[1] - e0;
    const float inv_res = 1.0f / res;
    const float C = 6.0f;                 // reference f32 erf saturates by |z|~5.5
    const int w = threadIdx.x >> 6;       // wave id within block

    const int stride = gridDim.x * blockDim.x;
    int i0 = blockIdx.x * blockDim.x + threadIdx.x;
    float xv = (i0 < n) ? x[i0 * 6] : 0.0f;       // AXIS=0 of row-major (N,6)
    for (int i = i0; i < n; i += stride) {
        int inx = i + stride;
        float xnext = (inx < n) ? x[inx * 6] : 0.0f;   // prefetch next point

        float t = (xv - e0) * inv_res;    // bin units; needed args are (j - t)
        int j0 = (int)ceilf(t - C - 1.0f);
        int j1 = (int)floorf(t + C);
        j0 = max(j0, 0);
        j1 = min(j1, NBINS - 1);
        if (j0 <= j1) {
            // table position of u0 = j0 - t; advances by exactly 16 per bin
            float pos = ((float)j0 - t - TBASE) * 16.0f;   // in [4, 212] by construction
            float fq = floorf(pos);
            float s = pos - fq;
            int q = (int)fq;
            // Catmull-Rom weights (constant across the 13 bins of this point)
            float s2 = s * s, s3 = s2 * s;
            float w0 = -0.5f * s + s2 - 0.5f * s3;
            float w1 = 1.0f - 2.5f * s2 + 1.5f * s3;
            float w2 = 0.5f * s + 2.0f * s2 - 1.5f * s3;
            float w3 = -0.5f * s2 + 0.5f * s3;
            for (int j = j0; j <= j1; ++j) {
                float v = w0 * G[q - 1] + w1 * G[q] + w2 * G[q + 1] + w3 * G[q + 2];
                unsafeAtomicAdd(&sh[w][j], v);   // native ds_add_f32
                q += 16;
            }
        }
        xv = xnext;
    }
    __syncthreads();

    // Flush block partials to private bin-major slice (plain stores, no zeroing).
    for (int j = threadIdx.x; j < NBINS; j += blockDim.x) {
        float v = sh[0][j] + sh[1][j] + sh[2][j] + sh[3][j];
        ws[j * nb + blockIdx.x] = v;
    }
}

// One block, 1024 threads = 16 waves. Each wave owns bins j = wave, wave+16, ...
// and reads that bin's nb partials fully coalesced (64 lanes x contiguous floats),
// then shuffle-reduces. High MLP, deterministic order.
__global__ __launch_bounds__(1024) void finalize_kernel(const float* __restrict__ ws,
                                                        const float* __restrict__ edges,
                                                        float* __restrict__ out, int nb) {
    __shared__ float vb[NBINS];
    __shared__ float tot[NBINS];
    const int tid = threadIdx.x;
    const int wave = tid >> 6;
    const int lane = tid & 63;

    for (int j = wave; j < NBINS; j += 16) {
        float acc = 0.0f;
        #pragma unroll 4
        for (int b = lane; b < nb; b += 64) acc += ws[j * nb + b];
        for (int off = 32; off > 0; off >>= 1) acc += __shfl_down(acc, off);
        if (lane == 0) vb[j] = acc;
    }
    __syncthreads();

    if (tid < NBINS) tot[tid] = vb[tid];
    __syncthreads();
    for (int off = NBINS / 2; off >= 1; off >>= 1) {
        if (tid < off) tot[tid] += tot[tid + off];
        __syncthreads();
    }
    if (tid < NBINS) {
        float resv = edges[1] - edges[0];
        out[tid] = vb[tid] / (tot[0] * resv);
    }
}

extern "C" void kernel_launch(void* const* d_in, const int* in_sizes, int n_in,
                              void* d_out, int out_size, void* d_ws, size_t ws_size,
                              hipStream_t stream) {
    const float* x     = (const float*)d_in[0];
    const float* edges = (const float*)d_in[1];
    float* out = (float*)d_out;
    float* ws  = (float*)d_ws;
    int n = in_sizes[0] / 6;

    int nb = (int)(ws_size / (NBINS * sizeof(float)));
    if (nb > MAXNB) nb = MAXNB;
    if (nb < 1) nb = 1;

    hist_kernel<<<nb, 256, 0, stream>>>(x, edges, ws, n, nb);
    finalize_kernel<<<1, 1024, 0, stream>>>(ws, edges, out, nb);
}

// Round 3
// 118.203 us; speedup vs baseline: 1.4088x; 1.2982x over previous
//
#include <hip/hip_runtime.h>
#include <math.h>

#define NBINS  128
#define DFINE  2272        // fine-grid cells (1/16 bin): d = floor(16*t)+DOFF, taps within [0,2268]
#define DOFF   118
#define GT_N   235         // g-table: G[m] = g((m-117)/16), covering |u| <= 7.3125 (g==0 beyond, f32-exact)
#define MAXNB  256
#define DPAD   2414        // DFINE + DFINE/16, +1-per-16 padded conv buffer (kills stride-16 bank conflicts)

// Scatter: hist[j] = sum_i g(j - t_i), g(u) = ndtr(u+1) - ndtr(u)  (bandwidth == resolution).
// Catmull-Rom in t on a 1/16-bin grid: g(j - t) = sum_m w_m(s) * g(j - (qf+m-1)/16), so each
// point deposits its 4 CR weights into fine cells qf-1..qf+2. Exact same accuracy as evaluating
// the interpolated table per bin (round 2, which passed), but 4 ds_adds/point instead of 65 DS
// ops, and same-address wave collisions drop ~50x (cells are 16x finer than bins).
__global__ __launch_bounds__(256) void hist_kernel(const float* __restrict__ x,
                                                   const float* __restrict__ edges,
                                                   float* __restrict__ ws, int n, int nb) {
    __shared__ float D[DFINE];
    for (int i = threadIdx.x; i < DFINE; i += 256) D[i] = 0.0f;
    __syncthreads();

    const float e0 = edges[0];
    const float res = edges[1] - e0;
    const float sc = 16.0f / res;                    // t16 = 16 * (x - e0)/res

    const int nth = nb * 256;
    for (int base = (blockIdx.x * 256 + threadIdx.x) * 4; base < n; base += nth * 4) {
        float xs[4];
        #pragma unroll
        for (int k = 0; k < 4; ++k) {                // 4 consecutive points: dense, coalesced, 4-deep MLP
            int idx = base + k;
            xs[k] = (idx < n) ? x[(size_t)idx * 6] : -1.0e9f;   // AXIS=0 of row-major (N,6)
        }
        #pragma unroll
        for (int k = 0; k < 4; ++k) {
            float t16 = (xs[k] - e0) * sc;
            float fq = floorf(t16);
            int qf = (int)fq;
            if (qf < -117 || qf > 2148) continue;    // contributes exactly 0 to every bin in f32
            float s = t16 - fq;
            float s2 = s * s, s3 = s2 * s;
            float w0 = fmaf(-0.5f, s3, s2) - 0.5f * s;
            float w1 = fmaf(1.5f, s3, fmaf(-2.5f, s2, 1.0f));
            float w2 = fmaf(-1.5f, s3, fmaf(2.0f, s2, 0.5f * s));
            float w3 = fmaf(0.5f, s3, -0.5f * s2);   // w0+w1+w2+w3 == 1 exactly
            int d = qf + DOFF;
            unsafeAtomicAdd(&D[d - 1], w0);          // native ds_add_f32, collisions ~never
            unsafeAtomicAdd(&D[d],     w1);
            unsafeAtomicAdd(&D[d + 1], w2);
            unsafeAtomicAdd(&D[d + 2], w3);
        }
    }
    __syncthreads();
    float* slice = ws + (size_t)blockIdx.x * DFINE;  // plain coalesced stores, no zeroing needed
    for (int i = threadIdx.x; i < DFINE; i += 256) slice[i] = D[i];
}

// Sum the nb block slices: thread d sums ws[b][d] over b (contiguous across threads -> coalesced).
__global__ __launch_bounds__(256) void reduce_kernel(const float* __restrict__ ws,
                                                     float* __restrict__ Dt, int nb) {
    int d = blockIdx.x * 256 + threadIdx.x;
    if (d >= DFINE) return;
    float a0 = 0.0f, a1 = 0.0f, a2 = 0.0f, a3 = 0.0f;
    int b = 0;
    for (; b + 4 <= nb; b += 4) {
        a0 += ws[(size_t)(b    ) * DFINE + d];
        a1 += ws[(size_t)(b + 1) * DFINE + d];
        a2 += ws[(size_t)(b + 2) * DFINE + d];
        a3 += ws[(size_t)(b + 3) * DFINE + d];
    }
    float acc = (a0 + a1) + (a2 + a3);
    for (; b < nb; ++b) acc += ws[(size_t)b * DFINE + d];
    Dt[d] = acc;
}

// Convolve fine density with g (235 taps/bin), normalize. Builds the erf table here (once).
__global__ __launch_bounds__(128) void final_kernel(const float* __restrict__ Dt,
                                                    const float* __restrict__ edges,
                                                    float* __restrict__ out) {
    __shared__ float G[GT_N];
    __shared__ float Ds[DPAD];
    __shared__ float hs[NBINS];
    const int t = threadIdx.x;                       // exactly 128 threads, thread t = bin t
    const float inv_sqrt2 = 0.70710678118654752440f;
    for (int k = t; k < GT_N; k += 128) {
        float u = (float)(k - 117) * 0.0625f;
        G[k] = 0.5f * (erff((u + 1.0f) * inv_sqrt2) - erff(u * inv_sqrt2));
    }
    for (int dd = t; dd < DFINE; dd += 128) Ds[dd + (dd >> 4)] = Dt[dd];  // +1/16 pad: conv reads
    __syncthreads();                                                      // hit distinct banks

    float acc = 0.0f;
    const int p0 = 16 * t;
    #pragma unroll 5
    for (int r = 1; r <= GT_N; ++r) {                // hist[t] = sum_r D[16t+r] * g-table[235-r]
        int idx = p0 + r;
        acc = fmaf(Ds[idx + (idx >> 4)], G[GT_N - r], acc);
    }
    hs[t] = acc;
    __syncthreads();
    for (int off = NBINS / 2; off >= 1; off >>= 1) {
        if (t < off) hs[t] += hs[t + off];
        __syncthreads();
    }
    float res = edges[1] - edges[0];
    out[t] = acc / (hs[0] * res);                    // mean factor 1/n cancels in normalization
}

extern "C" void kernel_launch(void* const* d_in, const int* in_sizes, int n_in,
                              void* d_out, int out_size, void* d_ws, size_t ws_size,
                              hipStream_t stream) {
    const float* x     = (const float*)d_in[0];
    const float* edges = (const float*)d_in[1];
    float* out = (float*)d_out;
    float* ws  = (float*)d_ws;
    int n = in_sizes[0] / 6;

    int nb = (int)(ws_size / (sizeof(float) * DFINE)) - 1;  // slices + 1 Dt buffer must fit
    if (nb > MAXNB) nb = MAXNB;
    if (nb < 1) nb = 1;
    float* Dt = ws + (size_t)nb * DFINE;

    hist_kernel<<<nb, 256, 0, stream>>>(x, edges, ws, n, nb);
    reduce_kernel<<<(DFINE + 255) / 256, 256, 0, stream>>>(ws, Dt, nb);
    final_kernel<<<1, 128, 0, stream>>>(Dt, edges, out);
}

// Round 4
// 110.424 us; speedup vs baseline: 1.5080x; 1.0704x over previous
//
#include <hip/hip_runtime.h>
#include <math.h>

#define NBINS  128
#define DFINE  2272        // fine-grid cells (1/16 bin): d = floor(16*t)+DOFF, taps within [0,2268]
#define DOFF   118
#define GT_N   235         // g-table: G[m] = g((m-117)/16); g==0 beyond |u|~7.3 in f32
#define NBMAX  1024        // hist blocks: 4 blocks/CU on 256 CUs (LDS 9KB/block -> fits easily)
#define NPART  8           // two-level reduce: 8 partial summers per fine cell
#define DPAD   2414        // DFINE + DFINE/16, +1-per-16 padded conv buffer (bank-conflict-free)

// Scatter: hist[j] = sum_i g(j - t_i), g(u) = ndtr(u+1) - ndtr(u)  (bandwidth == resolution).
// Each point deposits its 4 Catmull-Rom weights onto a 1/16-bin fine grid in LDS
// (4 native ds_add_f32, same-address wave collisions ~never), block flushes its
// private slice to ws with plain stores. Grid sized so each thread does ONE 4-point chunk.
__global__ __launch_bounds__(256) void hist_kernel(const float* __restrict__ x,
                                                   const float* __restrict__ edges,
                                                   float* __restrict__ ws, int n, int nb) {
    __shared__ float D[DFINE];
    for (int i = threadIdx.x; i < DFINE; i += 256) D[i] = 0.0f;
    __syncthreads();

    const float e0 = edges[0];
    const float res = edges[1] - e0;
    const float sc = 16.0f / res;                    // t16 = 16 * (x - e0)/res

    const int nth = nb * 256;
    for (int base = (blockIdx.x * 256 + threadIdx.x) * 4; base < n; base += nth * 4) {
        float xs[4];
        #pragma unroll
        for (int k = 0; k < 4; ++k) {                // 4 consecutive points: dense reads, 4-deep MLP
            int idx = base + k;
            xs[k] = (idx < n) ? x[(size_t)idx * 6] : -1.0e9f;   // AXIS=0 of row-major (N,6)
        }
        #pragma unroll
        for (int k = 0; k < 4; ++k) {
            float t16 = (xs[k] - e0) * sc;
            float fq = floorf(t16);
            int qf = (int)fq;
            if (qf < -117 || qf > 2148) continue;    // contributes exactly 0 to every bin in f32
            float s = t16 - fq;
            float s2 = s * s, s3 = s2 * s;
            float w0 = fmaf(-0.5f, s3, s2) - 0.5f * s;
            float w1 = fmaf(1.5f, s3, fmaf(-2.5f, s2, 1.0f));
            float w2 = fmaf(-1.5f, s3, fmaf(2.0f, s2, 0.5f * s));
            float w3 = fmaf(0.5f, s3, -0.5f * s2);   // w0+w1+w2+w3 == 1 exactly
            int d = qf + DOFF;
            unsafeAtomicAdd(&D[d - 1], w0);          // native ds_add_f32
            unsafeAtomicAdd(&D[d],     w1);
            unsafeAtomicAdd(&D[d + 1], w2);
            unsafeAtomicAdd(&D[d + 2], w3);
        }
    }
    __syncthreads();
    float* slice = ws + (size_t)blockIdx.x * DFINE;  // plain coalesced stores, no zeroing needed
    for (int i = threadIdx.x; i < DFINE; i += 256) slice[i] = D[i];
}

// Two-level reduce, level 1: thread (p,d) sums slices b = p, p+8, ... (128 slices each at
// nb=1024), consecutive threads share p and have consecutive d -> coalesced. 71 blocks.
__global__ __launch_bounds__(256) void reduce_kernel(const float* __restrict__ ws,
                                                     float* __restrict__ Pt, int nb) {
    int gid = blockIdx.x * 256 + threadIdx.x;
    if (gid >= DFINE * NPART) return;
    int p = gid / DFINE;
    int d = gid - p * DFINE;
    float a0 = 0.0f, a1 = 0.0f, a2 = 0.0f, a3 = 0.0f;
    int b = p;
    for (; b + 3 * NPART < nb; b += 4 * NPART) {     // 4-deep MLP
        a0 += ws[(size_t)(b            ) * DFINE + d];
        a1 += ws[(size_t)(b +     NPART) * DFINE + d];
        a2 += ws[(size_t)(b + 2 * NPART) * DFINE + d];
        a3 += ws[(size_t)(b + 3 * NPART) * DFINE + d];
    }
    float acc = (a0 + a1) + (a2 + a3);
    for (; b < nb; b += NPART) acc += ws[(size_t)b * DFINE + d];
    Pt[(size_t)p * DFINE + d] = acc;
}

// Level 2 + convolution + normalization in one 128-thread block. Builds erf table here (once).
__global__ __launch_bounds__(128) void final_kernel(const float* __restrict__ Pt,
                                                    const float* __restrict__ edges,
                                                    float* __restrict__ out) {
    __shared__ float G[GT_N];
    __shared__ float Ds[DPAD];
    __shared__ float hs[NBINS];
    const int t = threadIdx.x;                       // exactly 128 threads, thread t = bin t
    const float inv_sqrt2 = 0.70710678118654752440f;
    for (int k = t; k < GT_N; k += 128) {
        float u = (float)(k - 117) * 0.0625f;
        G[k] = 0.5f * (erff((u + 1.0f) * inv_sqrt2) - erff(u * inv_sqrt2));
    }
    for (int dd = t; dd < DFINE; dd += 128) {        // fold the 8 partials (72KB total read)
        float v = 0.0f;
        #pragma unroll
        for (int p = 0; p < NPART; ++p) v += Pt[(size_t)p * DFINE + dd];
        Ds[dd + (dd >> 4)] = v;                      // +1/16 pad: conv reads hit distinct banks
    }
    __syncthreads();

    float acc = 0.0f;
    const int p0 = 16 * t;
    #pragma unroll 5
    for (int r = 1; r <= GT_N; ++r) {                // hist[t] = sum_r D[16t+r] * g-table[235-r]
        int idx = p0 + r;
        acc = fmaf(Ds[idx + (idx >> 4)], G[GT_N - r], acc);
    }
    hs[t] = acc;
    __syncthreads();
    for (int off = NBINS / 2; off >= 1; off >>= 1) {
        if (t < off) hs[t] += hs[t + off];
        __syncthreads();
    }
    float res = edges[1] - edges[0];
    out[t] = acc / (hs[0] * res);                    // mean factor 1/n cancels in normalization
}

extern "C" void kernel_launch(void* const* d_in, const int* in_sizes, int n_in,
                              void* d_out, int out_size, void* d_ws, size_t ws_size,
                              hipStream_t stream) {
    const float* x     = (const float*)d_in[0];
    const float* edges = (const float*)d_in[1];
    float* out = (float*)d_out;
    float* ws  = (float*)d_ws;
    int n = in_sizes[0] / 6;

    // slices + NPART partial buffers must fit in the workspace
    int nb = (int)(ws_size / (sizeof(float) * DFINE)) - NPART;
    if (nb > NBMAX) nb = NBMAX;
    if (nb < 1) nb = 1;
    float* Pt = ws + (size_t)nb * DFINE;

    hist_kernel<<<nb, 256, 0, stream>>>(x, edges, ws, n, nb);
    reduce_kernel<<<(DFINE * NPART + 255) / 256, 256, 0, stream>>>(ws, Pt, nb);
    final_kernel<<<1, 128, 0, stream>>>(Pt, edges, out);
}

// Round 5
// 105.258 us; speedup vs baseline: 1.5820x; 1.0491x over previous
//
#include <hip/hip_runtime.h>
#include <math.h>

#define NBINS  128
#define DFINE  2272        // fine-grid cells (1/16 bin): d = floor(16*t)+DOFF, taps within [0,2268]
#define DOFF   118
#define GT_N   235         // g-table: G[m] = g((m-117)/16); g==0 beyond |u|~7.3 in f32
#define NB     512         // 2 blocks/CU: halves zero+flush DS overhead vs 1024, keeps 8 waves/CU
#define DPAD   2414        // DFINE + DFINE/16, +1-per-16 padded conv buffer (bank-conflict-free)

// Clear the single global fine-grid accumulator (harness poisons ws between runs).
__global__ __launch_bounds__(256) void zero_kernel(float* __restrict__ Dt) {
    int i = blockIdx.x * 256 + threadIdx.x;
    if (i < DFINE) Dt[i] = 0.0f;
}

// Scatter: hist[j] = sum_i g(j - t_i), g(u) = ndtr(u+1) - ndtr(u)  (bandwidth == resolution).
// Each point deposits its 4 Catmull-Rom weights onto a 1/16-bin fine grid in LDS
// (4 native ds_add_f32, same-address wave collisions ~never). Block then flushes its
// grid straight into the single global accumulator with native global_atomic_add_f32
// (<=512 adds/address, fire-and-forget) -- no per-block slices, no reduce kernel.
__global__ __launch_bounds__(256) void hist_kernel(const float* __restrict__ x,
                                                   const float* __restrict__ edges,
                                                   float* __restrict__ Dt, int n) {
    __shared__ float D[DFINE];
    for (int i = threadIdx.x; i < DFINE; i += 256) D[i] = 0.0f;
    __syncthreads();

    const float e0 = edges[0];
    const float res = edges[1] - e0;
    const float sc = 16.0f / res;                    // t16 = 16 * (x - e0)/res

    const int nth = NB * 256;
    for (int base = (blockIdx.x * 256 + threadIdx.x) * 4; base < n; base += nth * 4) {
        float xs[4];
        #pragma unroll
        for (int k = 0; k < 4; ++k) {                // 4 consecutive points: dense reads, 4-deep MLP
            int idx = base + k;
            xs[k] = (idx < n) ? x[(size_t)idx * 6] : -1.0e9f;   // AXIS=0 of row-major (N,6)
        }
        #pragma unroll
        for (int k = 0; k < 4; ++k) {
            float t16 = (xs[k] - e0) * sc;
            float fq = floorf(t16);
            int qf = (int)fq;
            if (qf < -117 || qf > 2148) continue;    // contributes exactly 0 to every bin in f32
            float s = t16 - fq;
            float s2 = s * s, s3 = s2 * s;
            float w0 = fmaf(-0.5f, s3, s2) - 0.5f * s;
            float w1 = fmaf(1.5f, s3, fmaf(-2.5f, s2, 1.0f));
            float w2 = fmaf(-1.5f, s3, fmaf(2.0f, s2, 0.5f * s));
            float w3 = fmaf(0.5f, s3, -0.5f * s2);   // w0+w1+w2+w3 == 1 exactly
            int d = qf + DOFF;
            unsafeAtomicAdd(&D[d - 1], w0);          // native ds_add_f32
            unsafeAtomicAdd(&D[d],     w1);
            unsafeAtomicAdd(&D[d + 1], w2);
            unsafeAtomicAdd(&D[d + 2], w3);
        }
    }
    __syncthreads();
    for (int i = threadIdx.x; i < DFINE; i += 256) { // coalesced atomic flush, skip empty cells
        float v = D[i];
        if (v != 0.0f) unsafeAtomicAdd(&Dt[i], v);   // native global_atomic_add_f32 (no return)
    }
}

// Convolution + normalization in one 128-thread block. Builds the erf table here (once).
__global__ __launch_bounds__(128) void final_kernel(const float* __restrict__ Dt,
                                                    const float* __restrict__ edges,
                                                    float* __restrict__ out) {
    __shared__ float G[GT_N];
    __shared__ float Ds[DPAD];
    __shared__ float hs[NBINS];
    const int t = threadIdx.x;                       // exactly 128 threads, thread t = bin t
    const float inv_sqrt2 = 0.70710678118654752440f;
    for (int k = t; k < GT_N; k += 128) {
        float u = (float)(k - 117) * 0.0625f;
        G[k] = 0.5f * (erff((u + 1.0f) * inv_sqrt2) - erff(u * inv_sqrt2));
    }
    for (int dd = t; dd < DFINE; dd += 128)
        Ds[dd + (dd >> 4)] = Dt[dd];                 // +1/16 pad: conv reads hit distinct banks
    __syncthreads();

    float acc = 0.0f;
    const int p0 = 16 * t;
    #pragma unroll 5
    for (int r = 1; r <= GT_N; ++r) {                // hist[t] = sum_r D[16t+r] * g-table[235-r]
        int idx = p0 + r;
        acc = fmaf(Ds[idx + (idx >> 4)], G[GT_N - r], acc);
    }
    hs[t] = acc;
    __syncthreads();
    for (int off = NBINS / 2; off >= 1; off >>= 1) {
        if (t < off) hs[t] += hs[t + off];
        __syncthreads();
    }
    float res = edges[1] - edges[0];
    out[t] = acc / (hs[0] * res);                    // mean factor 1/n cancels in normalization
}

extern "C" void kernel_launch(void* const* d_in, const int* in_sizes, int n_in,
                              void* d_out, int out_size, void* d_ws, size_t ws_size,
                              hipStream_t stream) {
    const float* x     = (const float*)d_in[0];
    const float* edges = (const float*)d_in[1];
    float* out = (float*)d_out;
    float* Dt  = (float*)d_ws;                       // 2272 floats of workspace used
    int n = in_sizes[0] / 6;

    zero_kernel<<<(DFINE + 255) / 256, 256, 0, stream>>>(Dt);
    hist_kernel<<<NB, 256, 0, stream>>>(x, edges, Dt, n);
    final_kernel<<<1, 128, 0, stream>>>(Dt, edges, out);
}